// Round 1
// baseline (135.467 us; speedup 1.0000x reference)
//
#include <hip/hip_runtime.h>
#include <hip/hip_bf16.h>
#include <stdint.h>

typedef __attribute__((ext_vector_type(8))) short bf16x8;
typedef __attribute__((ext_vector_type(8))) short short8;
typedef __attribute__((ext_vector_type(4))) float f32x4;

#define M_DIM 512
#define N_DIM 4096
#define K_DIM 11008
#define BM 128
#define BN 128
#define BK 64
#define KSTEPS (K_DIM / BK)   // 172

#define GLOBAL_AS(p) ((const __attribute__((address_space(1))) void*)(p))
#define LDS_AS(p)    ((__attribute__((address_space(3))) void*)(p))

// round-to-nearest-even fp32 -> bf16 bits
__device__ __forceinline__ short f2bf(float f) {
    unsigned u = __float_as_uint(f);
    unsigned r = u + 0x7fff + ((u >> 16) & 1);
    return (short)(r >> 16);
}

// ---------------- Kernel 1: groupwise fake-quant of weight, fp32 -> bf16 ----------------
// Groups of 64 contiguous elems. Each lane: 8 elems; 8 lanes per group; wave = 8 groups (512 elems).
__global__ __launch_bounds__(256) void quant_w(const float* __restrict__ w, short* __restrict__ wq) {
    const int lane = threadIdx.x & 63;
    const int wid  = threadIdx.x >> 6;
    const long long total = (long long)N_DIM * K_DIM;   // 45,088,768 (divisible by 2048)
    for (long long base = (long long)blockIdx.x * 2048 + (long long)wid * 512;
         base < total;
         base += (long long)gridDim.x * 2048) {
        long long e0 = base + (long long)lane * 8;
        const float4* p = (const float4*)(w + e0);
        float4 v0 = p[0];
        float4 v1 = p[1];
        float vals[8] = {v0.x, v0.y, v0.z, v0.w, v1.x, v1.y, v1.z, v1.w};
        float mn = vals[0], mx = vals[0];
        #pragma unroll
        for (int j = 1; j < 8; ++j) { mn = fminf(mn, vals[j]); mx = fmaxf(mx, vals[j]); }
        // reduce across the 8 lanes sharing one group (lane>>3 identical)
        #pragma unroll
        for (int m = 1; m <= 4; m <<= 1) {
            mn = fminf(mn, __shfl_xor(mn, m, 64));
            mx = fmaxf(mx, __shfl_xor(mx, m, 64));
        }
        float scale = fmaxf(mx - mn, 1e-5f) / 15.0f;
        float zp = rintf(-mn / scale);
        short8 s;
        #pragma unroll
        for (int j = 0; j < 8; ++j) {
            float q = rintf(vals[j] / scale) + zp;
            q = fminf(fmaxf(q, 0.0f), 15.0f);
            s[j] = f2bf((q - zp) * scale);
        }
        *(short8*)(wq + e0) = s;
    }
}

// ---------------- Kernel 2: x fp32 -> bf16 ----------------
__global__ __launch_bounds__(256) void conv_x(const float* __restrict__ x, short* __restrict__ xb) {
    const long long total = (long long)M_DIM * K_DIM;   // 5,636,096 (divisible by 8)
    for (long long e0 = ((long long)blockIdx.x * 256 + threadIdx.x) * 8;
         e0 < total;
         e0 += (long long)gridDim.x * 256 * 8) {
        const float4* p = (const float4*)(x + e0);
        float4 v0 = p[0];
        float4 v1 = p[1];
        short8 s;
        s[0] = f2bf(v0.x); s[1] = f2bf(v0.y); s[2] = f2bf(v0.z); s[3] = f2bf(v0.w);
        s[4] = f2bf(v1.x); s[5] = f2bf(v1.y); s[6] = f2bf(v1.z); s[7] = f2bf(v1.w);
        *(short8*)(xb + e0) = s;
    }
}

// ---------------- Kernel 3: bf16 GEMM (A [M,K], B [N,K] both K-major), split-K partials ----------------
// 256 threads = 4 waves in 2x2; wave tile 64x64 = 4x4 frags of mfma 16x16x32 bf16.
// LDS linear [rows][BK], staged via global_load_lds (16B/lane), with 8-elem-slot XOR swizzle
// applied on the GLOBAL source address and on the ds_read address (LDS dest stays linear).
__global__ __launch_bounds__(256) void gemm_bt(const short* __restrict__ A,
                                               const short* __restrict__ B,
                                               float* __restrict__ P,
                                               int spb) {
    __shared__ short As[BM * BK];
    __shared__ short Bs[BN * BK];
    const int tid  = threadIdx.x;
    const int lane = tid & 63;
    const int w    = tid >> 6;
    const int wr   = w >> 1;
    const int wc   = w & 1;
    const int m0   = blockIdx.y * BM;
    const int n0   = blockIdx.x * BN;
    const int split = blockIdx.z;
    const int kt0 = split * spb;
    const int kt1 = min(kt0 + spb, KSTEPS);

    f32x4 acc[4][4] = {};

    const int srow = lane >> 3;   // row within an instruction's 8-row chunk
    const int slot = lane & 7;    // 8-elem slot within a 64-elem row
    const int frA  = wr * 64 + (lane & 15);
    const int frB  = wc * 64 + (lane & 15);
    const int qb   = lane >> 4;   // k-slot base for fragment reads

    for (int kt = kt0; kt < kt1; ++kt) {
        const int kcol = kt * BK;
        #pragma unroll
        for (int i = 0; i < 4; ++i) {
            const int rb  = (w * 4 + i) * 8;         // 8 rows per instruction
            const int row = rb + srow;
            const int gcol = ((slot ^ (row & 7)) * 8);
            __builtin_amdgcn_global_load_lds(
                GLOBAL_AS(A + (size_t)(m0 + row) * K_DIM + kcol + gcol),
                LDS_AS(As + rb * 64), 16, 0, 0);
        }
        #pragma unroll
        for (int i = 0; i < 4; ++i) {
            const int rb  = (w * 4 + i) * 8;
            const int row = rb + srow;
            const int gcol = ((slot ^ (row & 7)) * 8);
            __builtin_amdgcn_global_load_lds(
                GLOBAL_AS(B + (size_t)(n0 + row) * K_DIM + kcol + gcol),
                LDS_AS(Bs + rb * 64), 16, 0, 0);
        }
        __syncthreads();
        #pragma unroll
        for (int ks = 0; ks < 2; ++ks) {
            bf16x8 af[4], bfr[4];
            #pragma unroll
            for (int fm = 0; fm < 4; ++fm) {
                const int r = frA + fm * 16;
                const int q = ks * 4 + qb;
                af[fm] = *(const bf16x8*)(As + r * 64 + (q ^ (r & 7)) * 8);
            }
            #pragma unroll
            for (int fn = 0; fn < 4; ++fn) {
                const int r = frB + fn * 16;
                const int q = ks * 4 + qb;
                bfr[fn] = *(const bf16x8*)(Bs + r * 64 + (q ^ (r & 7)) * 8);
            }
            #pragma unroll
            for (int fm = 0; fm < 4; ++fm)
                #pragma unroll
                for (int fn = 0; fn < 4; ++fn)
                    acc[fm][fn] = __builtin_amdgcn_mfma_f32_16x16x32_bf16(af[fm], bfr[fn], acc[fm][fn], 0, 0, 0);
        }
        __syncthreads();
    }

    float* out = P + (size_t)split * M_DIM * N_DIM;
    #pragma unroll
    for (int fm = 0; fm < 4; ++fm) {
        #pragma unroll
        for (int fn = 0; fn < 4; ++fn) {
            const int col  = n0 + wc * 64 + fn * 16 + (lane & 15);
            const int rowb = m0 + wr * 64 + fm * 16 + (lane >> 4) * 4;
            #pragma unroll
            for (int r = 0; r < 4; ++r) {
                out[(size_t)(rowb + r) * N_DIM + col] = acc[fm][fn][r];
            }
        }
    }
}

// ---------------- Kernel 4: reduce split-K partials + bias ----------------
__global__ __launch_bounds__(256) void reduce_out(const float* __restrict__ P,
                                                  const float* __restrict__ bias,
                                                  float* __restrict__ out,
                                                  int splitk) {
    const size_t total = (size_t)M_DIM * N_DIM;   // 2,097,152
    for (size_t idx4 = ((size_t)blockIdx.x * 256 + threadIdx.x) * 4;
         idx4 < total;
         idx4 += (size_t)gridDim.x * 256 * 4) {
        const int col = (int)(idx4 % N_DIM);
        float4 b = *(const float4*)(bias + col);
        float4 s = b;
        for (int sp = 0; sp < splitk; ++sp) {
            float4 p = *(const float4*)(P + (size_t)sp * total + idx4);
            s.x += p.x; s.y += p.y; s.z += p.z; s.w += p.w;
        }
        *(float4*)(out + idx4) = s;
    }
}

extern "C" void kernel_launch(void* const* d_in, const int* in_sizes, int n_in,
                              void* d_out, int out_size, void* d_ws, size_t ws_size,
                              hipStream_t stream) {
    const float* x    = (const float*)d_in[0];
    const float* wgt  = (const float*)d_in[1];
    const float* bias = (const float*)d_in[2];
    float* out = (float*)d_out;

    char* ws = (char*)d_ws;
    const size_t wq_bytes = (size_t)N_DIM * K_DIM * 2;   // 90,177,536
    const size_t xb_bytes = (size_t)M_DIM * K_DIM * 2;   // 11,272,192
    short* wq  = (short*)ws;
    short* xb  = (short*)(ws + wq_bytes);
    float* part = (float*)(ws + wq_bytes + xb_bytes);

    const size_t per_split = (size_t)M_DIM * N_DIM * 4;  // 8,388,608
    size_t avail = (ws_size > wq_bytes + xb_bytes) ? (ws_size - wq_bytes - xb_bytes) : 0;
    int splitk = (int)(avail / per_split);
    if (splitk > 4) splitk = 4;
    if (splitk < 1) splitk = 1;
    const int spb = (KSTEPS + splitk - 1) / splitk;

    hipLaunchKernelGGL(quant_w, dim3(2048), dim3(256), 0, stream, wgt, wq);
    hipLaunchKernelGGL(conv_x,  dim3(2048), dim3(256), 0, stream, x, xb);
    hipLaunchKernelGGL(gemm_bt, dim3(N_DIM / BN, M_DIM / BM, splitk), dim3(256), 0, stream,
                       xb, wq, part, spb);
    hipLaunchKernelGGL(reduce_out, dim3(2048), dim3(256), 0, stream, part, bias, out, splitk);
}

// Round 2
// 128.781 us; speedup vs baseline: 1.0519x; 1.0519x over previous
//
#include <hip/hip_runtime.h>
#include <hip/hip_bf16.h>
#include <stdint.h>

typedef __attribute__((ext_vector_type(8))) short bf16x8;
typedef __attribute__((ext_vector_type(8))) short short8;
typedef __attribute__((ext_vector_type(4))) float f32x4;

#define M_DIM 512
#define N_DIM 4096
#define K_DIM 11008
#define KSTEPS 172   // K_DIM / 64

#define GLOBAL_AS(p) ((const __attribute__((address_space(1))) void*)(p))
#define LDS_AS(p)    ((__attribute__((address_space(3))) void*)(p))

// round-to-nearest-even fp32 -> bf16 bits
__device__ __forceinline__ short f2bf(float f) {
    unsigned u = __float_as_uint(f);
    unsigned r = u + 0x7fff + ((u >> 16) & 1);
    return (short)(r >> 16);
}

__device__ __forceinline__ void fence_bar() {
    asm volatile("" ::: "memory");
    __builtin_amdgcn_s_barrier();
    asm volatile("" ::: "memory");
}

// ---------------- Kernel 1: groupwise fake-quant of weight, fp32 -> bf16 ----------------
__global__ __launch_bounds__(256) void quant_w(const float* __restrict__ w, short* __restrict__ wq) {
    const int lane = threadIdx.x & 63;
    const int wid  = threadIdx.x >> 6;
    const long long total = (long long)N_DIM * K_DIM;
    for (long long base = (long long)blockIdx.x * 2048 + (long long)wid * 512;
         base < total;
         base += (long long)gridDim.x * 2048) {
        long long e0 = base + (long long)lane * 8;
        const float4* p = (const float4*)(w + e0);
        float4 v0 = p[0];
        float4 v1 = p[1];
        float vals[8] = {v0.x, v0.y, v0.z, v0.w, v1.x, v1.y, v1.z, v1.w};
        float mn = vals[0], mx = vals[0];
        #pragma unroll
        for (int j = 1; j < 8; ++j) { mn = fminf(mn, vals[j]); mx = fmaxf(mx, vals[j]); }
        #pragma unroll
        for (int m = 1; m <= 4; m <<= 1) {
            mn = fminf(mn, __shfl_xor(mn, m, 64));
            mx = fmaxf(mx, __shfl_xor(mx, m, 64));
        }
        float scale = fmaxf(mx - mn, 1e-5f) / 15.0f;
        float zp = rintf(-mn / scale);
        short8 s;
        #pragma unroll
        for (int j = 0; j < 8; ++j) {
            float q = rintf(vals[j] / scale) + zp;
            q = fminf(fmaxf(q, 0.0f), 15.0f);
            s[j] = f2bf((q - zp) * scale);
        }
        *(short8*)(wq + e0) = s;
    }
}

// ---------------- Kernel 2: x fp32 -> bf16 ----------------
__global__ __launch_bounds__(256) void conv_x(const float* __restrict__ x, short* __restrict__ xb) {
    const long long total = (long long)M_DIM * K_DIM;
    for (long long e0 = ((long long)blockIdx.x * 256 + threadIdx.x) * 8;
         e0 < total;
         e0 += (long long)gridDim.x * 256 * 8) {
        const float4* p = (const float4*)(x + e0);
        float4 v0 = p[0];
        float4 v1 = p[1];
        short8 s;
        s[0] = f2bf(v0.x); s[1] = f2bf(v0.y); s[2] = f2bf(v0.z); s[3] = f2bf(v0.w);
        s[4] = f2bf(v1.x); s[5] = f2bf(v1.y); s[6] = f2bf(v1.z); s[7] = f2bf(v1.w);
        *(short8*)(xb + e0) = s;
    }
}

// ---------------- Kernel 3: 256x256 8-phase bf16 GEMM with split-K ----------------
// A [M,K] bf16, B [N,K] bf16 (both K-major). 512 threads = 8 waves (2M x 4N).
// Per-wave C: 128x64 = 8(fm) x 4(fn) frags of mfma 16x16x32. LDS: 2 dbuf x (A,B) x 256x64 bf16 = 128 KiB.

template<int QD>
__device__ __forceinline__ void phase_reads(const short* __restrict__ Asd,
                                            const short* __restrict__ Bsd,
                                            int arow, int brow, int qb,
                                            bf16x8 (&af)[2][2], bf16x8 (&bfr)[2][4]) {
    if (QD == 0) {
        #pragma unroll
        for (int ks = 0; ks < 2; ++ks)
            #pragma unroll
            for (int fn = 0; fn < 4; ++fn) {
                const int r = brow + fn * 16;
                bfr[ks][fn] = *(const bf16x8*)&Bsd[r * 64 + (((ks * 4 + qb) ^ (r & 7)) * 8)];
            }
    }
    #pragma unroll
    for (int ks = 0; ks < 2; ++ks)
        #pragma unroll
        for (int j = 0; j < 2; ++j) {
            const int r = arow + (QD * 2 + j) * 16;
            af[ks][j] = *(const bf16x8*)&Asd[r * 64 + (((ks * 4 + qb) ^ (r & 7)) * 8)];
        }
}

template<int QD>
__device__ __forceinline__ void phase_mfma(const bf16x8 (&af)[2][2], const bf16x8 (&bfr)[2][4],
                                           f32x4 (&acc)[8][4]) {
    __builtin_amdgcn_s_setprio(1);
    #pragma unroll
    for (int ks = 0; ks < 2; ++ks)
        #pragma unroll
        for (int j = 0; j < 2; ++j)
            #pragma unroll
            for (int fn = 0; fn < 4; ++fn)
                acc[QD * 2 + j][fn] = __builtin_amdgcn_mfma_f32_16x16x32_bf16(
                    af[ks][j], bfr[ks][fn], acc[QD * 2 + j][fn], 0, 0, 0);
    __builtin_amdgcn_s_setprio(0);
}

__global__ __launch_bounds__(512) void gemm8(const short* __restrict__ A,
                                             const short* __restrict__ B,
                                             float* __restrict__ P,
                                             int spb) {
    __shared__ short As[2][256 * 64];
    __shared__ short Bs[2][256 * 64];
    const int tid  = threadIdx.x;
    const int lane = tid & 63;
    const int w    = tid >> 6;
    const int wr   = w >> 2;     // 0..1
    const int wc   = w & 3;      // 0..3
    const int m0   = blockIdx.y * 256;
    const int n0   = blockIdx.x * 256;
    const int kt0  = blockIdx.z * spb;
    const int kt1  = min(kt0 + spb, KSTEPS);   // (kt1-kt0) even, >= 2 by construction

    const int srow = tid >> 3;                       // 0..63
    const int sswz = (tid & 7) ^ (srow & 7);         // swizzled 8-elem slot for staging source
    const int arow = wr * 128 + (lane & 15);
    const int brow = wc * 64 + (lane & 15);
    const int qb   = lane >> 4;

    f32x4  acc[8][4] = {};
    bf16x8 bfr[2][4];
    bf16x8 af[2][2];

    auto stageA = [&](int d, int h, int kt) {
        #pragma unroll
        for (int l = 0; l < 2; ++l) {
            __builtin_amdgcn_global_load_lds(
                GLOBAL_AS(A + (size_t)(m0 + h * 128 + l * 64 + srow) * K_DIM + kt * 64 + sswz * 8),
                LDS_AS(&As[d][(h * 128 + l * 64 + w * 8) * 64]), 16, 0, 0);
        }
    };
    auto stageB = [&](int d, int h, int kt) {
        #pragma unroll
        for (int l = 0; l < 2; ++l) {
            __builtin_amdgcn_global_load_lds(
                GLOBAL_AS(B + (size_t)(n0 + h * 128 + l * 64 + srow) * K_DIM + kt * 64 + sswz * 8),
                LDS_AS(&Bs[d][(h * 128 + l * 64 + w * 8) * 64]), 16, 0, 0);
        }
    };

    // ---- prologue: t0 full -> buf0; t1's two B halves -> buf1 ----
    stageB(0, 0, kt0); stageB(0, 1, kt0);
    stageA(0, 0, kt0); stageA(0, 1, kt0);
    stageB(1, 0, kt0 + 1); stageB(1, 1, kt0 + 1);
    asm volatile("s_waitcnt vmcnt(4)" ::: "memory");   // t0 fully landed
    fence_bar();

    for (int t0 = kt0; t0 < kt1; t0 += 2) {
        const int t1 = t0 + 1;
        const int t2 = (t0 + 2 < kt1) ? t0 + 2 : kt1 - 1;   // clamped dummy on last iter
        const int t3 = (t0 + 3 < kt1) ? t0 + 3 : kt1 - 1;

        // ---- K-tile t0 from buf0 ----
        // P0
        phase_reads<0>(As[0], Bs[0], arow, brow, qb, af, bfr);
        stageA(1, 0, t1);
        fence_bar();
        asm volatile("s_waitcnt lgkmcnt(0)" ::: "memory");
        phase_mfma<0>(af, bfr, acc);
        fence_bar();
        // P1
        phase_reads<1>(As[0], Bs[0], arow, brow, qb, af, bfr);
        stageA(1, 1, t1);
        stageB(0, 0, t2);
        fence_bar();
        asm volatile("s_waitcnt lgkmcnt(0)" ::: "memory");
        phase_mfma<1>(af, bfr, acc);
        fence_bar();
        // P2
        phase_reads<2>(As[0], Bs[0], arow, brow, qb, af, bfr);
        stageB(0, 1, t2);
        fence_bar();
        asm volatile("s_waitcnt lgkmcnt(0)" ::: "memory");
        phase_mfma<2>(af, bfr, acc);
        fence_bar();
        // P3
        phase_reads<3>(As[0], Bs[0], arow, brow, qb, af, bfr);
        fence_bar();
        asm volatile("s_waitcnt lgkmcnt(0)" ::: "memory");
        phase_mfma<3>(af, bfr, acc);
        asm volatile("s_waitcnt vmcnt(4)" ::: "memory");   // t1 fully landed
        fence_bar();

        // ---- K-tile t1 from buf1 ----
        // P4
        phase_reads<0>(As[1], Bs[1], arow, brow, qb, af, bfr);
        stageA(0, 0, t2);
        fence_bar();
        asm volatile("s_waitcnt lgkmcnt(0)" ::: "memory");
        phase_mfma<0>(af, bfr, acc);
        fence_bar();
        // P5
        phase_reads<1>(As[1], Bs[1], arow, brow, qb, af, bfr);
        stageA(0, 1, t2);
        stageB(1, 0, t3);
        fence_bar();
        asm volatile("s_waitcnt lgkmcnt(0)" ::: "memory");
        phase_mfma<1>(af, bfr, acc);
        fence_bar();
        // P6
        phase_reads<2>(As[1], Bs[1], arow, brow, qb, af, bfr);
        stageB(1, 1, t3);
        fence_bar();
        asm volatile("s_waitcnt lgkmcnt(0)" ::: "memory");
        phase_mfma<2>(af, bfr, acc);
        fence_bar();
        // P7
        phase_reads<3>(As[1], Bs[1], arow, brow, qb, af, bfr);
        fence_bar();
        asm volatile("s_waitcnt lgkmcnt(0)" ::: "memory");
        phase_mfma<3>(af, bfr, acc);
        asm volatile("s_waitcnt vmcnt(4)" ::: "memory");   // t2 fully landed
        fence_bar();
    }

    asm volatile("s_waitcnt vmcnt(0)" ::: "memory");   // drain dummy stages before retire

    float* out = P + (size_t)blockIdx.z * M_DIM * N_DIM;
    #pragma unroll
    for (int fm = 0; fm < 8; ++fm) {
        #pragma unroll
        for (int fn = 0; fn < 4; ++fn) {
            const int col  = n0 + wc * 64 + fn * 16 + (lane & 15);
            const int rowb = m0 + wr * 128 + fm * 16 + (lane >> 4) * 4;
            #pragma unroll
            for (int r = 0; r < 4; ++r) {
                out[(size_t)(rowb + r) * N_DIM + col] = acc[fm][fn][r];
            }
        }
    }
}

// ---------------- Kernel 4: reduce split-K partials + bias ----------------
__global__ __launch_bounds__(256) void reduce_out(const float* __restrict__ P,
                                                  const float* __restrict__ bias,
                                                  float* __restrict__ out,
                                                  int splitk) {
    const size_t total = (size_t)M_DIM * N_DIM;
    for (size_t idx4 = ((size_t)blockIdx.x * 256 + threadIdx.x) * 4;
         idx4 < total;
         idx4 += (size_t)gridDim.x * 256 * 4) {
        const int col = (int)(idx4 % N_DIM);
        float4 b = *(const float4*)(bias + col);
        float4 s = b;
        for (int sp = 0; sp < splitk; ++sp) {
            float4 p = *(const float4*)(P + (size_t)sp * total + idx4);
            s.x += p.x; s.y += p.y; s.z += p.z; s.w += p.w;
        }
        *(float4*)(out + idx4) = s;
    }
}

extern "C" void kernel_launch(void* const* d_in, const int* in_sizes, int n_in,
                              void* d_out, int out_size, void* d_ws, size_t ws_size,
                              hipStream_t stream) {
    const float* x    = (const float*)d_in[0];
    const float* wgt  = (const float*)d_in[1];
    const float* bias = (const float*)d_in[2];
    float* out = (float*)d_out;

    char* ws = (char*)d_ws;
    const size_t wq_bytes = (size_t)N_DIM * K_DIM * 2;
    const size_t xb_bytes = (size_t)M_DIM * K_DIM * 2;
    short* wq  = (short*)ws;
    short* xb  = (short*)(ws + wq_bytes);
    float* part = (float*)(ws + wq_bytes + xb_bytes);

    const size_t per_split = (size_t)M_DIM * N_DIM * 4;
    size_t avail = (ws_size > wq_bytes + xb_bytes) ? (ws_size - wq_bytes - xb_bytes) : 0;

    // largest splitk in [1,8] that fits, with even steps-per-split and every split >= 2 K-tiles
    int splitk = 1, spb = KSTEPS;
    for (int sk = 8; sk >= 1; --sk) {
        if ((size_t)sk * per_split > avail) continue;
        int s = (KSTEPS + sk - 1) / sk;
        if (s & 1) s++;
        int last = KSTEPS - (sk - 1) * s;
        if (last < 2) continue;
        splitk = sk; spb = s;
        break;
    }

    hipLaunchKernelGGL(quant_w, dim3(2048), dim3(256), 0, stream, wgt, wq);
    hipLaunchKernelGGL(conv_x,  dim3(2048), dim3(256), 0, stream, x, xb);
    hipLaunchKernelGGL(gemm8, dim3(N_DIM / 256, M_DIM / 256, splitk), dim3(512), 0, stream,
                       xb, wq, part, spb);
    hipLaunchKernelGGL(reduce_out, dim3(2048), dim3(256), 0, stream, part, bias, out, splitk);
}

// Round 3
// 122.134 us; speedup vs baseline: 1.1092x; 1.0544x over previous
//
#include <hip/hip_runtime.h>
#include <hip/hip_bf16.h>
#include <stdint.h>

typedef __attribute__((ext_vector_type(8))) short bf16x8;
typedef __attribute__((ext_vector_type(8))) short short8;
typedef __attribute__((ext_vector_type(4))) float f32x4;

#define M_DIM 512
#define N_DIM 4096
#define K_DIM 11008
#define KSTEPS 172   // K_DIM / 64

#define GLOBAL_AS(p) ((const __attribute__((address_space(1))) void*)(p))
#define LDS_AS(p)    ((__attribute__((address_space(3))) void*)(p))

// round-to-nearest-even fp32 -> bf16 bits
__device__ __forceinline__ short f2bf(float f) {
    unsigned u = __float_as_uint(f);
    unsigned r = u + 0x7fff + ((u >> 16) & 1);
    return (short)(r >> 16);
}

__device__ __forceinline__ void fence_bar() {
    asm volatile("" ::: "memory");
    __builtin_amdgcn_s_barrier();
    asm volatile("" ::: "memory");
}
#define LGKM0() asm volatile("s_waitcnt lgkmcnt(0)" ::: "memory")
#define VMCNT(n) asm volatile("s_waitcnt vmcnt(" #n ")" ::: "memory")

// ---------------- Kernel 1: x fp32 -> bf16 ----------------
__global__ __launch_bounds__(256) void conv_x(const float* __restrict__ x, short* __restrict__ xb) {
    const long long total = (long long)M_DIM * K_DIM;
    for (long long e0 = ((long long)blockIdx.x * 256 + threadIdx.x) * 8;
         e0 < total;
         e0 += (long long)gridDim.x * 256 * 8) {
        const float4* p = (const float4*)(x + e0);
        float4 v0 = p[0];
        float4 v1 = p[1];
        short8 s;
        s[0] = f2bf(v0.x); s[1] = f2bf(v0.y); s[2] = f2bf(v0.z); s[3] = f2bf(v0.w);
        s[4] = f2bf(v1.x); s[5] = f2bf(v1.y); s[6] = f2bf(v1.z); s[7] = f2bf(v1.w);
        *(short8*)(xb + e0) = s;
    }
}

// ---------------- Kernel 2: fused fake-quant + 256x256 8-phase bf16 GEMM, split-K ----------------
// A = xb [M,K] bf16 (global_load_lds staging, XOR-swizzled source).
// B = W  [N,K] fp32, quantized on the fly per 64-elem K-group (== BK) during reg-staging.
// 512 threads = 8 waves (2M x 4N); per-wave C 128x64 = 8x4 frags of mfma 16x16x32.
// LDS: 2 dbuf x (A,B) x 256x64 bf16 = 128 KiB. Partials written as bf16.

template<int QD>
__device__ __forceinline__ void phase_reads(const short* __restrict__ Asd,
                                            const short* __restrict__ Bsd,
                                            int arow, int brow, int qb,
                                            bf16x8 (&af)[2][2], bf16x8 (&bfr)[2][4]) {
    if (QD == 0) {
        #pragma unroll
        for (int ks = 0; ks < 2; ++ks)
            #pragma unroll
            for (int fn = 0; fn < 4; ++fn) {
                const int r = brow + fn * 16;
                bfr[ks][fn] = *(const bf16x8*)&Bsd[r * 64 + (((ks * 4 + qb) ^ (r & 7)) * 8)];
            }
    }
    #pragma unroll
    for (int ks = 0; ks < 2; ++ks)
        #pragma unroll
        for (int j = 0; j < 2; ++j) {
            const int r = arow + (QD * 2 + j) * 16;
            af[ks][j] = *(const bf16x8*)&Asd[r * 64 + (((ks * 4 + qb) ^ (r & 7)) * 8)];
        }
}

template<int QD>
__device__ __forceinline__ void phase_mfma(const bf16x8 (&af)[2][2], const bf16x8 (&bfr)[2][4],
                                           f32x4 (&acc)[8][4]) {
    __builtin_amdgcn_s_setprio(1);
    #pragma unroll
    for (int ks = 0; ks < 2; ++ks)
        #pragma unroll
        for (int j = 0; j < 2; ++j)
            #pragma unroll
            for (int fn = 0; fn < 4; ++fn)
                acc[QD * 2 + j][fn] = __builtin_amdgcn_mfma_f32_16x16x32_bf16(
                    af[ks][j], bfr[ks][fn], acc[QD * 2 + j][fn], 0, 0, 0);
    __builtin_amdgcn_s_setprio(0);
}

__global__ __launch_bounds__(512, 2) void gemm_fq(const short* __restrict__ A,
                                                  const float* __restrict__ W,
                                                  unsigned short* __restrict__ P,
                                                  int spb) {
    __shared__ short As[2][256 * 64];
    __shared__ short Bs[2][256 * 64];
    const int tid  = threadIdx.x;
    const int lane = tid & 63;
    const int w    = tid >> 6;
    const int wr   = w >> 2;     // 0..1
    const int wc   = w & 3;      // 0..3
    const int m0   = blockIdx.y * 256;
    const int n0   = blockIdx.x * 256;
    const int kt0  = blockIdx.z * spb;
    const int kt1  = min(kt0 + spb, KSTEPS);

    const int srow = tid >> 3;                       // 0..63   (A staging)
    const int sswz = (tid & 7) ^ (srow & 7);         // swizzled 8-elem slot, A staging source
    const int rB   = tid >> 2;                       // 0..127  (B staging: row within half)
    const int qB   = tid & 3;                        // quarter of the 64-elem group
    const int arow = wr * 128 + (lane & 15);
    const int brow = wc * 64 + (lane & 15);
    const int qb   = lane >> 4;

    f32x4  acc[8][4] = {};
    bf16x8 bfr[2][4];
    bf16x8 af[2][2];
    float4 bA[4], bB[4];   // staged fp32 B (half0 / half1), static indexing only

    auto stageA = [&](int d, int h, int kt) {
        #pragma unroll
        for (int l = 0; l < 2; ++l) {
            __builtin_amdgcn_global_load_lds(
                GLOBAL_AS(A + (size_t)(m0 + h * 128 + l * 64 + srow) * K_DIM + kt * 64 + sswz * 8),
                LDS_AS(&As[d][(h * 128 + l * 64 + w * 8) * 64]), 16, 0, 0);
        }
    };
    auto loadB = [&](float4 (&dst)[4], int h, int kt) {
        const float* src = W + (size_t)(n0 + h * 128 + rB) * K_DIM + kt * 64 + qB * 16;
        dst[0] = *(const float4*)(src + 0);
        dst[1] = *(const float4*)(src + 4);
        dst[2] = *(const float4*)(src + 8);
        dst[3] = *(const float4*)(src + 12);
    };
    auto quantWrite = [&](const float4 (&v)[4], int h, short* BsF) {
        float4 lo4 = v[0], hi4 = v[0];
        #pragma unroll
        for (int j = 1; j < 4; ++j) {
            lo4.x = fminf(lo4.x, v[j].x); lo4.y = fminf(lo4.y, v[j].y);
            lo4.z = fminf(lo4.z, v[j].z); lo4.w = fminf(lo4.w, v[j].w);
            hi4.x = fmaxf(hi4.x, v[j].x); hi4.y = fmaxf(hi4.y, v[j].y);
            hi4.z = fmaxf(hi4.z, v[j].z); hi4.w = fmaxf(hi4.w, v[j].w);
        }
        float mn = fminf(fminf(lo4.x, lo4.y), fminf(lo4.z, lo4.w));
        float mx = fmaxf(fmaxf(hi4.x, hi4.y), fmaxf(hi4.z, hi4.w));
        mn = fminf(mn, __shfl_xor(mn, 1, 64));
        mn = fminf(mn, __shfl_xor(mn, 2, 64));
        mx = fmaxf(mx, __shfl_xor(mx, 1, 64));
        mx = fmaxf(mx, __shfl_xor(mx, 2, 64));
        float scale = fmaxf(mx - mn, 1e-5f) * (1.0f / 15.0f);
        float rs = 1.0f / scale;                      // one precise div per group-quarter
        float zp = rintf(-mn * rs);
        short8 s0, s1;
        #pragma unroll
        for (int j = 0; j < 8; ++j) {
            float val = (j < 4) ? ((const float*)&v[0])[j] : ((const float*)&v[1])[j - 4];
            float q = rintf(val * rs) + zp;
            q = fminf(fmaxf(q, 0.0f), 15.0f);
            s0[j] = f2bf((q - zp) * scale);
        }
        #pragma unroll
        for (int j = 0; j < 8; ++j) {
            float val = (j < 4) ? ((const float*)&v[2])[j] : ((const float*)&v[3])[j - 4];
            float q = rintf(val * rs) + zp;
            q = fminf(fmaxf(q, 0.0f), 15.0f);
            s1[j] = f2bf((q - zp) * scale);
        }
        const int row  = h * 128 + rB;
        const int base = row * 64;
        *(short8*)&BsF[base + (((qB * 2 + 0) ^ (rB & 7)) * 8)] = s0;
        *(short8*)&BsF[base + (((qB * 2 + 1) ^ (rB & 7)) * 8)] = s1;
    };

    // ---- prologue: tile kt0 into buf0, prefill Bh0(kt0+1) ----
    loadB(bA, 0, kt0);
    loadB(bB, 1, kt0);
    VMCNT(4);
    quantWrite(bA, 0, Bs[0]);
    VMCNT(0);
    quantWrite(bB, 1, Bs[0]);
    stageA(0, 0, kt0);
    stageA(0, 1, kt0);
    loadB(bA, 0, (kt0 + 1 < kt1) ? kt0 + 1 : kt0);
    VMCNT(4);   // A(kt0) landed (leaves Bh0' 4)
    LGKM0();    // B ds_writes done
    fence_bar();

    int par = 0;
    for (int t = kt0; t < kt1; ++t) {
        const int tn  = (t + 1 < kt1) ? t + 1 : kt1 - 1;
        const int tn2 = (t + 2 < kt1) ? t + 2 : kt1 - 1;
        const short* Asc = As[par];
        const short* Bsc = Bs[par];
        short* Bsf = Bs[par ^ 1];
        // P0
        phase_reads<0>(Asc, Bsc, arow, brow, qb, af, bfr);
        loadB(bB, 1, tn);
        fence_bar();
        LGKM0();
        phase_mfma<0>(af, bfr, acc);
        fence_bar();
        // P1
        phase_reads<1>(Asc, Bsc, arow, brow, qb, af, bfr);
        VMCNT(4);                     // Bh0(tn) landed (leaves Bh1 4)
        quantWrite(bA, 0, Bsf);
        stageA(par ^ 1, 0, tn);
        fence_bar();
        LGKM0();
        phase_mfma<1>(af, bfr, acc);
        fence_bar();
        // P2
        phase_reads<2>(Asc, Bsc, arow, brow, qb, af, bfr);
        VMCNT(2);                     // Bh1(tn) landed (leaves A glds 2)
        quantWrite(bB, 1, Bsf);
        stageA(par ^ 1, 1, tn);
        fence_bar();
        LGKM0();
        phase_mfma<2>(af, bfr, acc);
        fence_bar();
        // P3
        phase_reads<3>(Asc, Bsc, arow, brow, qb, af, bfr);
        loadB(bA, 0, tn2);
        fence_bar();
        LGKM0();
        phase_mfma<3>(af, bfr, acc);
        VMCNT(4);                     // A(tn) landed (leaves Bh0(tn2) 4)
        fence_bar();
        par ^= 1;
    }

    VMCNT(0);   // drain dummy stages before retire

    unsigned short* out = P + (size_t)blockIdx.z * M_DIM * N_DIM;
    #pragma unroll
    for (int fm = 0; fm < 8; ++fm) {
        #pragma unroll
        for (int fn = 0; fn < 4; ++fn) {
            const int col  = n0 + wc * 64 + fn * 16 + (lane & 15);
            const int rowb = m0 + wr * 128 + fm * 16 + (lane >> 4) * 4;
            #pragma unroll
            for (int r = 0; r < 4; ++r) {
                out[(size_t)(rowb + r) * N_DIM + col] = (unsigned short)f2bf(acc[fm][fn][r]);
            }
        }
    }
}

// ---------------- Kernel 3: reduce bf16 split-K partials + bias ----------------
__global__ __launch_bounds__(256) void reduce_out(const unsigned short* __restrict__ P,
                                                  const float* __restrict__ bias,
                                                  float* __restrict__ out,
                                                  int splitk) {
    const size_t total = (size_t)M_DIM * N_DIM;
    for (size_t idx8 = ((size_t)blockIdx.x * 256 + threadIdx.x) * 8;
         idx8 < total;
         idx8 += (size_t)gridDim.x * 256 * 8) {
        const int col = (int)(idx8 % N_DIM);
        float s[8];
        {
            float4 b0 = *(const float4*)(bias + col);
            float4 b1 = *(const float4*)(bias + col + 4);
            s[0] = b0.x; s[1] = b0.y; s[2] = b0.z; s[3] = b0.w;
            s[4] = b1.x; s[5] = b1.y; s[6] = b1.z; s[7] = b1.w;
        }
        for (int sp = 0; sp < splitk; ++sp) {
            short8 p = *(const short8*)(P + (size_t)sp * total + idx8);
            #pragma unroll
            for (int j = 0; j < 8; ++j)
                s[j] += __uint_as_float(((unsigned)(unsigned short)p[j]) << 16);
        }
        float4 o0 = {s[0], s[1], s[2], s[3]};
        float4 o1 = {s[4], s[5], s[6], s[7]};
        *(float4*)(out + idx8) = o0;
        *(float4*)(out + idx8 + 4) = o1;
    }
}

extern "C" void kernel_launch(void* const* d_in, const int* in_sizes, int n_in,
                              void* d_out, int out_size, void* d_ws, size_t ws_size,
                              hipStream_t stream) {
    const float* x    = (const float*)d_in[0];
    const float* wgt  = (const float*)d_in[1];
    const float* bias = (const float*)d_in[2];
    float* out = (float*)d_out;

    char* ws = (char*)d_ws;
    const size_t xb_bytes = (size_t)M_DIM * K_DIM * 2;          // 11,272,192
    short* xb = (short*)ws;
    unsigned short* part = (unsigned short*)(ws + xb_bytes);

    const size_t per_split = (size_t)M_DIM * N_DIM * 2;         // 4 MiB (bf16)
    size_t avail = (ws_size > xb_bytes) ? (ws_size - xb_bytes) : 0;
    int splitk = 8;
    while (splitk > 1 && (size_t)splitk * per_split > avail) splitk--;
    const int spb = (KSTEPS + splitk - 1) / splitk;

    hipLaunchKernelGGL(conv_x, dim3(2048), dim3(256), 0, stream, x, xb);
    hipLaunchKernelGGL(gemm_fq, dim3(N_DIM / 256, M_DIM / 256, splitk), dim3(512), 0, stream,
                       xb, wgt, part, spb);
    hipLaunchKernelGGL(reduce_out, dim3(1024), dim3(256), 0, stream, part, bias, out, splitk);
}

// Round 4
// 90.022 us; speedup vs baseline: 1.5048x; 1.3567x over previous
//
#include <hip/hip_runtime.h>
#include <hip/hip_bf16.h>
#include <stdint.h>

typedef __attribute__((ext_vector_type(8))) short bf16x8;
typedef __attribute__((ext_vector_type(8))) short short8;
typedef __attribute__((ext_vector_type(4))) float f32x4;

#define M_DIM 512
#define N_DIM 4096
#define K_DIM 11008
#define KSTEPS 172   // K_DIM / 64

#define GLOBAL_AS(p) ((const __attribute__((address_space(1))) void*)(p))
#define LDS_AS(p)    ((__attribute__((address_space(3))) void*)(p))

// round-to-nearest-even fp32 -> bf16 bits
__device__ __forceinline__ short f2bf(float f) {
    unsigned u = __float_as_uint(f);
    unsigned r = u + 0x7fff + ((u >> 16) & 1);
    return (short)(r >> 16);
}

__device__ __forceinline__ unsigned cvt_pk_bf16(float lo, float hi) {
    unsigned r;
    asm("v_cvt_pk_bf16_f32 %0, %1, %2" : "=v"(r) : "v"(lo), "v"(hi));
    return r;
}

__device__ __forceinline__ void fence_bar() {
    asm volatile("" ::: "memory");
    __builtin_amdgcn_s_barrier();
    asm volatile("" ::: "memory");
}
#define LGKM0() asm volatile("s_waitcnt lgkmcnt(0)" ::: "memory")
#define VMCNT(n) asm volatile("s_waitcnt vmcnt(" #n ")" ::: "memory")

// ---------------- Kernel 1: x fp32 -> bf16 ----------------
__global__ __launch_bounds__(256) void conv_x(const float* __restrict__ x, short* __restrict__ xb) {
    const long long total = (long long)M_DIM * K_DIM;
    for (long long e0 = ((long long)blockIdx.x * 256 + threadIdx.x) * 8;
         e0 < total;
         e0 += (long long)gridDim.x * 256 * 8) {
        const float4* p = (const float4*)(x + e0);
        float4 v0 = p[0];
        float4 v1 = p[1];
        short8 s;
        s[0] = f2bf(v0.x); s[1] = f2bf(v0.y); s[2] = f2bf(v0.z); s[3] = f2bf(v0.w);
        s[4] = f2bf(v1.x); s[5] = f2bf(v1.y); s[6] = f2bf(v1.z); s[7] = f2bf(v1.w);
        *(short8*)(xb + e0) = s;
    }
}

// ---------------- Kernel 2: fused fake-quant + 256x256 8-phase bf16 GEMM, split-K ----------------
// A = xb [M,K] bf16 via global_load_lds (XOR-swizzled source).
// B = W [N,K] fp32, reg-staged in 4 chunks/tile (64 rows each), quantized per 64-elem K-group
// (group == BK) 4 phases after load. 512 threads = 8 waves (2M x 4N); wave C = 128x64.
// LDS: 2 dbuf x (A,B) x 256x64 bf16 = 128 KiB. Partials written bf16.

template<int QD>
__device__ __forceinline__ void phase_reads(const short* __restrict__ Asd,
                                            const short* __restrict__ Bsd,
                                            int arow, int brow, int qb,
                                            bf16x8 (&af)[2][2], bf16x8 (&bfr)[2][4]) {
    if (QD == 0) {
        #pragma unroll
        for (int ks = 0; ks < 2; ++ks)
            #pragma unroll
            for (int fn = 0; fn < 4; ++fn) {
                const int r = brow + fn * 16;
                bfr[ks][fn] = *(const bf16x8*)&Bsd[r * 64 + (((ks * 4 + qb) ^ (r & 7)) * 8)];
            }
    }
    #pragma unroll
    for (int ks = 0; ks < 2; ++ks)
        #pragma unroll
        for (int j = 0; j < 2; ++j) {
            const int r = arow + (QD * 2 + j) * 16;
            af[ks][j] = *(const bf16x8*)&Asd[r * 64 + (((ks * 4 + qb) ^ (r & 7)) * 8)];
        }
}

template<int QD>
__device__ __forceinline__ void phase_mfma(const bf16x8 (&af)[2][2], const bf16x8 (&bfr)[2][4],
                                           f32x4 (&acc)[8][4]) {
    __builtin_amdgcn_s_setprio(1);
    #pragma unroll
    for (int ks = 0; ks < 2; ++ks)
        #pragma unroll
        for (int j = 0; j < 2; ++j)
            #pragma unroll
            for (int fn = 0; fn < 4; ++fn)
                acc[QD * 2 + j][fn] = __builtin_amdgcn_mfma_f32_16x16x32_bf16(
                    af[ks][j], bfr[ks][fn], acc[QD * 2 + j][fn], 0, 0, 0);
    __builtin_amdgcn_s_setprio(0);
}

__global__ __launch_bounds__(512, 2) void gemm_fq(const short* __restrict__ A,
                                                  const float* __restrict__ W,
                                                  unsigned short* __restrict__ P,
                                                  int spb) {
    __shared__ short As[2][256 * 64];
    __shared__ short Bs[2][256 * 64];
    const int tid  = threadIdx.x;
    const int lane = tid & 63;
    const int w    = tid >> 6;
    const int wr   = w >> 2;     // 0..1
    const int wc   = w & 3;      // 0..3
    const int m0   = blockIdx.y * 256;
    const int n0   = blockIdx.x * 256;
    const int kt0  = blockIdx.z * spb;
    const int kt1  = min(kt0 + spb, KSTEPS);

    const int srow = tid >> 3;                       // 0..63  (A staging)
    const int sswz = (tid & 7) ^ (srow & 7);         // A staging source swizzle
    const int rQ   = tid >> 3;                       // 0..63  (B chunk row)
    const int sQ   = tid & 7;                        // 8-float slot within 64-group
    const int arow = wr * 128 + (lane & 15);
    const int brow = wc * 64 + (lane & 15);
    const int qb   = lane >> 4;

    f32x4  acc[8][4] = {};
    bf16x8 bfr[2][4];
    bf16x8 af[2][2];
    float4 c0[2], c1[2], c2[2], c3[2];   // 4 B-chunk reg sets, static indexing

    auto stageA = [&](int d, int h, int kt) {
        #pragma unroll
        for (int l = 0; l < 2; ++l) {
            __builtin_amdgcn_global_load_lds(
                GLOBAL_AS(A + (size_t)(m0 + h * 128 + l * 64 + srow) * K_DIM + kt * 64 + sswz * 8),
                LDS_AS(&As[d][(h * 128 + l * 64 + w * 8) * 64]), 16, 0, 0);
        }
    };
    auto loadBq = [&](float4 (&dst)[2], int c, int kt) {
        const float* src = W + (size_t)(n0 + c * 64 + rQ) * K_DIM + kt * 64 + sQ * 8;
        dst[0] = *(const float4*)(src);
        dst[1] = *(const float4*)(src + 4);
    };
    auto quantC = [&](const float4 (&v)[2], int c, short* BsF) {
        float mn = fminf(fminf(fminf(v[0].x, v[0].y), fminf(v[0].z, v[0].w)),
                         fminf(fminf(v[1].x, v[1].y), fminf(v[1].z, v[1].w)));
        float mx = fmaxf(fmaxf(fmaxf(v[0].x, v[0].y), fmaxf(v[0].z, v[0].w)),
                         fmaxf(fmaxf(v[1].x, v[1].y), fmaxf(v[1].z, v[1].w)));
        // 8-lane group reduce: DPP quad xor1, xor2, then ds_swizzle xor4
        mn = fminf(mn, __int_as_float(__builtin_amdgcn_mov_dpp(__float_as_int(mn), 0xB1, 0xf, 0xf, true)));
        mx = fmaxf(mx, __int_as_float(__builtin_amdgcn_mov_dpp(__float_as_int(mx), 0xB1, 0xf, 0xf, true)));
        mn = fminf(mn, __int_as_float(__builtin_amdgcn_mov_dpp(__float_as_int(mn), 0x4E, 0xf, 0xf, true)));
        mx = fmaxf(mx, __int_as_float(__builtin_amdgcn_mov_dpp(__float_as_int(mx), 0x4E, 0xf, 0xf, true)));
        mn = fminf(mn, __int_as_float(__builtin_amdgcn_ds_swizzle(__float_as_int(mn), 0x101F)));
        mx = fmaxf(mx, __int_as_float(__builtin_amdgcn_ds_swizzle(__float_as_int(mx), 0x101F)));
        float range = fmaxf(mx - mn, 1e-5f);
        float scale = range * (1.0f / 15.0f);
        float rs    = 15.0f / range;
        float zp    = rintf(-mn * rs);
        const float lo = -zp, hi = 15.0f - zp;
        const float* pv = (const float*)&v[0];
        float q[8];
        #pragma unroll
        for (int j = 0; j < 8; ++j)
            q[j] = fminf(fmaxf(rintf(pv[j] * rs), lo), hi) * scale;
        union { unsigned u[4]; short8 s; } pk;
        #pragma unroll
        for (int j = 0; j < 4; ++j)
            pk.u[j] = cvt_pk_bf16(q[2 * j], q[2 * j + 1]);
        const int r = c * 64 + rQ;
        *(short8*)&BsF[r * 64 + ((sQ ^ (r & 7)) * 8)] = pk.s;
    };

    // ---- prologue: tile kt0 -> buf0; preload chunks of kt0+1 ----
    loadBq(c0, 0, kt0); loadBq(c1, 1, kt0); loadBq(c2, 2, kt0); loadBq(c3, 3, kt0);
    stageA(0, 0, kt0); stageA(0, 1, kt0);
    VMCNT(10); quantC(c0, 0, Bs[0]);
    VMCNT(8);  quantC(c1, 1, Bs[0]);
    VMCNT(6);  quantC(c2, 2, Bs[0]);
    VMCNT(4);  quantC(c3, 3, Bs[0]);
    {
        const int t1 = kt0 + 1;   // exists: every split has >= 2 tiles
        loadBq(c0, 0, t1); loadBq(c1, 1, t1); loadBq(c2, 2, t1); loadBq(c3, 3, t1);
    }
    VMCNT(8);   // A(kt0) landed
    VMCNT(6);   // c0(kt0+1) landed -> loop invariant [c1,c2,c3]
    LGKM0();
    fence_bar();

    int par = 0;
    for (int t = kt0; t < kt1; ++t) {
        const int tn  = (t + 1 < kt1) ? t + 1 : t;        // A stage target (dummy on last)
        const int tn2 = (t + 2 < kt1) ? t + 2 : kt1 - 1;  // B chunk loads (dummy on tail)
        const short* Asc = As[par];
        const short* Bsc = Bs[par];
        short* Bsn = Bs[par ^ 1];
        // P0
        phase_reads<0>(Asc, Bsc, arow, brow, qb, af, bfr);
        quantC(c0, 0, Bsn);
        stageA(par ^ 1, 0, tn);
        loadBq(c0, 0, tn2);
        fence_bar(); LGKM0();
        phase_mfma<0>(af, bfr, acc);
        fence_bar();
        // P1
        phase_reads<1>(Asc, Bsc, arow, brow, qb, af, bfr);
        VMCNT(8);                    // c1 landed
        quantC(c1, 1, Bsn);
        stageA(par ^ 1, 1, tn);
        loadBq(c1, 1, tn2);
        fence_bar(); LGKM0();
        phase_mfma<1>(af, bfr, acc);
        fence_bar();
        // P2
        phase_reads<2>(Asc, Bsc, arow, brow, qb, af, bfr);
        VMCNT(10);                   // c2 landed
        quantC(c2, 2, Bsn);
        loadBq(c2, 2, tn2);
        fence_bar(); LGKM0();
        phase_mfma<2>(af, bfr, acc);
        fence_bar();
        // P3
        phase_reads<3>(Asc, Bsc, arow, brow, qb, af, bfr);
        VMCNT(10);                   // c3 landed
        quantC(c3, 3, Bsn);
        loadBq(c3, 3, tn2);
        fence_bar(); LGKM0();
        phase_mfma<3>(af, bfr, acc);
        VMCNT(6);                    // A(t+1) landed; leaves [c1,c2,c3]
        fence_bar();
        par ^= 1;
    }

    VMCNT(0);

    unsigned short* out = P + (size_t)blockIdx.z * M_DIM * N_DIM;
    #pragma unroll
    for (int fm = 0; fm < 8; ++fm) {
        #pragma unroll
        for (int fn = 0; fn < 4; ++fn) {
            const int col  = n0 + wc * 64 + fn * 16 + (lane & 15);
            const int rowb = m0 + wr * 128 + fm * 16 + (lane >> 4) * 4;
            #pragma unroll
            for (int r = 0; r < 4; ++r) {
                out[(size_t)(rowb + r) * N_DIM + col] = (unsigned short)f2bf(acc[fm][fn][r]);
            }
        }
    }
}

// ---------------- Kernel 3: reduce bf16 split-K partials + bias ----------------
__global__ __launch_bounds__(256) void reduce_out(const unsigned short* __restrict__ P,
                                                  const float* __restrict__ bias,
                                                  float* __restrict__ out,
                                                  int splitk) {
    const size_t total = (size_t)M_DIM * N_DIM;
    for (size_t idx8 = ((size_t)blockIdx.x * 256 + threadIdx.x) * 8;
         idx8 < total;
         idx8 += (size_t)gridDim.x * 256 * 8) {
        const int col = (int)(idx8 % N_DIM);
        float s[8];
        {
            float4 b0 = *(const float4*)(bias + col);
            float4 b1 = *(const float4*)(bias + col + 4);
            s[0] = b0.x; s[1] = b0.y; s[2] = b0.z; s[3] = b0.w;
            s[4] = b1.x; s[5] = b1.y; s[6] = b1.z; s[7] = b1.w;
        }
        for (int sp = 0; sp < splitk; ++sp) {
            short8 p = *(const short8*)(P + (size_t)sp * total + idx8);
            #pragma unroll
            for (int j = 0; j < 8; ++j)
                s[j] += __uint_as_float(((unsigned)(unsigned short)p[j]) << 16);
        }
        float4 o0 = {s[0], s[1], s[2], s[3]};
        float4 o1 = {s[4], s[5], s[6], s[7]};
        *(float4*)(out + idx8) = o0;
        *(float4*)(out + idx8 + 4) = o1;
    }
}

extern "C" void kernel_launch(void* const* d_in, const int* in_sizes, int n_in,
                              void* d_out, int out_size, void* d_ws, size_t ws_size,
                              hipStream_t stream) {
    const float* x    = (const float*)d_in[0];
    const float* wgt  = (const float*)d_in[1];
    const float* bias = (const float*)d_in[2];
    float* out = (float*)d_out;

    char* ws = (char*)d_ws;
    const size_t xb_bytes = (size_t)M_DIM * K_DIM * 2;          // 11,272,192
    short* xb = (short*)ws;
    unsigned short* part = (unsigned short*)(ws + xb_bytes);

    const size_t per_split = (size_t)M_DIM * N_DIM * 2;         // 4 MiB (bf16)
    size_t avail = (ws_size > xb_bytes) ? (ws_size - xb_bytes) : 0;
    // largest splitk in [1,8] that fits, with even steps-per-split and every split >= 2 K-tiles
    int splitk = 1, spb = KSTEPS;
    for (int sk = 8; sk >= 1; --sk) {
        if ((size_t)sk * per_split > avail) continue;
        int s = (KSTEPS + sk - 1) / sk;
        if (s & 1) s++;
        int last = KSTEPS - (sk - 1) * s;
        if (last < 2) continue;
        splitk = sk; spb = s;
        break;
    }

    hipLaunchKernelGGL(conv_x, dim3(2048), dim3(256), 0, stream, x, xb);
    hipLaunchKernelGGL(gemm_fq, dim3(N_DIM / 256, M_DIM / 256, splitk), dim3(512), 0, stream,
                       xb, wgt, part, spb);
    hipLaunchKernelGGL(reduce_out, dim3(1024), dim3(256), 0, stream, part, bias, out, splitk);
}